// Round 10
// baseline (437.908 us; speedup 1.0000x reference)
//
#include <hip/hip_runtime.h>
#include <hip/hip_bf16.h>

#define T_STEPS 100
#define BATCH   256
#define IN_DIM  784
#define HID_DIM 1024
#define OUT_DIM 10
#define M_ROWS  (T_STEPS * BATCH)   // 25600
#define KPAD    800                 // IN_DIM padded to multiple of 32
#define NITER   (KPAD / 32)         // 25
#define DECAY   0.6f
#define THRESH  0.9f

typedef __attribute__((ext_vector_type(8))) short bf16x8;
typedef __attribute__((ext_vector_type(4))) float f32x4;

// pack 8 fp32 (two float4) -> 8 bf16 (uint4) by truncation; exact for {0,1}
#define PACK8(dstp, v0, v1)                                                                        \
    {                                                                                              \
        unsigned int p0 = __builtin_amdgcn_perm(__builtin_bit_cast(unsigned int, (v0).y),          \
                                                __builtin_bit_cast(unsigned int, (v0).x), 0x07060302u); \
        unsigned int p1 = __builtin_amdgcn_perm(__builtin_bit_cast(unsigned int, (v0).w),          \
                                                __builtin_bit_cast(unsigned int, (v0).z), 0x07060302u); \
        unsigned int p2 = __builtin_amdgcn_perm(__builtin_bit_cast(unsigned int, (v1).y),          \
                                                __builtin_bit_cast(unsigned int, (v1).x), 0x07060302u); \
        unsigned int p3 = __builtin_amdgcn_perm(__builtin_bit_cast(unsigned int, (v1).w),          \
                                                __builtin_bit_cast(unsigned int, (v1).z), 0x07060302u); \
        *(uint4*)(dstp) = make_uint4(p0, p1, p2, p3);                                              \
    }

// ---------------------------------------------------------------------------
// W1 transpose + hi/lo bf16 split:  W1[784][1024] fp32
//   -> Th[1024][800] bf16 (W_hi), Tl[1024][800] bf16 (W - W_hi); k>=784 zeroed.
// x in {0,1} is exact in bf16 -> x@Wh + x@Wl reproduces fp32 GEMM to ~1e-5.
// ---------------------------------------------------------------------------
__global__ __launch_bounds__(256) void w1_split_T(const float* __restrict__ W1,
                                                  unsigned short* __restrict__ Th,
                                                  unsigned short* __restrict__ Tl) {
    __shared__ unsigned short lh[32][33];
    __shared__ unsigned short ll[32][33];
    const int nb = blockIdx.x * 32;
    const int kb = blockIdx.y * 32;
    const int t  = threadIdx.x;
    const int ln = t & 31, lk = t >> 5;
    #pragma unroll
    for (int i = 0; i < 4; ++i) {
        const int k = kb + lk + i * 8;
        const float w = (k < IN_DIM) ? W1[(size_t)k * HID_DIM + nb + ln] : 0.f;
        __hip_bfloat16 h = __float2bfloat16(w);
        float hf = __bfloat162float(h);
        __hip_bfloat16 l = __float2bfloat16(w - hf);
        lh[lk + i * 8][ln] = __builtin_bit_cast(unsigned short, h);
        ll[lk + i * 8][ln] = __builtin_bit_cast(unsigned short, l);
    }
    __syncthreads();
    const int o_n = t >> 3;
    const int o_k = (t & 7) * 4;
    ushort4 vh, vl;
    vh.x = lh[o_k + 0][o_n]; vh.y = lh[o_k + 1][o_n];
    vh.z = lh[o_k + 2][o_n]; vh.w = lh[o_k + 3][o_n];
    vl.x = ll[o_k + 0][o_n]; vl.y = ll[o_k + 1][o_n];
    vl.z = ll[o_k + 2][o_n]; vl.w = ll[o_k + 3][o_n];
    *(ushort4*)&Th[(size_t)(nb + o_n) * KPAD + kb + o_k] = vh;
    *(ushort4*)&Tl[(size_t)(nb + o_n) * KPAD + kb + o_k] = vl;
}

// ---------------------------------------------------------------------------
// GEMM1 (MFMA) — R5 verbatim (best measured: 147 us):
// 128x128 tile, BK=32, 4 waves, XOR-swizzled LDS (0 bank conflicts),
// register prefetch of next K-tile, single buffer, 2 barriers/iter,
// XCD-partitioned grid. R6/R8/R9 all proved deviations regress:
// deeper pipelines get sunk by the compiler (VGPR stays 84), smaller
// tiles amplify writes, double-buffer LDS halves residency.
// ---------------------------------------------------------------------------
#define LOADTILE(KT)                                                        \
    {                                                                       \
        const int  _c0 = (KT) + sc * 8;                                     \
        const bool _v0 = _c0 < IN_DIM, _v1 = (_c0 + 4) < IN_DIM;            \
        xa0 = _v0 ? *(const float4*)&Xa[(KT)]     : f4z;                    \
        xa1 = _v1 ? *(const float4*)&Xa[(KT) + 4] : f4z;                    \
        xb0 = _v0 ? *(const float4*)&Xb[(KT)]     : f4z;                    \
        xb1 = _v1 ? *(const float4*)&Xb[(KT) + 4] : f4z;                    \
        vh0 = *(const uint4*)&Ha[(KT)];  vh1 = *(const uint4*)&Hb[(KT)];    \
        vl0 = *(const uint4*)&La[(KT)];  vl1 = *(const uint4*)&Lb[(KT)];    \
    }

#define STORETILE()                                                         \
    {                                                                       \
        PACK8(&As[w0], xa0, xa1);                                           \
        PACK8(&As[w1], xb0, xb1);                                           \
        *(uint4*)&Bhs[w0] = vh0;  *(uint4*)&Bhs[w1] = vh1;                  \
        *(uint4*)&Bls[w0] = vl0;  *(uint4*)&Bls[w1] = vl1;                  \
    }

__global__ __launch_bounds__(256, 3) void gemm1_mfma(const float* __restrict__ X,
                                                     const unsigned short* __restrict__ Th,
                                                     const unsigned short* __restrict__ Tl,
                                                     float* __restrict__ C) {
    __shared__ unsigned short As[128 * 32];    // 8 KB
    __shared__ unsigned short Bhs[128 * 32];   // 8 KB
    __shared__ unsigned short Bls[128 * 32];   // 8 KB

    const int tid = threadIdx.x;
    const int bid = blockIdx.x;
    const int xcd = bid & 7;                   // hw XCD round-robin
    const int j_  = bid >> 3;                  // 0..199
    const int m0  = (xcd * 25 + (j_ >> 3)) * 128;
    const int n0  = (j_ & 7) * 128;

    const int lane = tid & 63, wv = tid >> 6;
    const int wm   = (wv & 1) * 64, wn = (wv >> 1) * 64;
    const int ml   = lane & 15, quad = lane >> 4;

    const int sr = tid >> 2;                   // 0..63
    const int sc = tid & 3;
    const int f0 = (sr >> 1) & 3;              // f(sr+64) == f(sr)
    const int w0 = sr * 32 + ((sc ^ f0) * 8);
    const int w1 = (sr + 64) * 32 + ((sc ^ f0) * 8);

    const float*          Xa = X  + (size_t)(m0 + sr)      * IN_DIM + sc * 8;
    const float*          Xb = X  + (size_t)(m0 + sr + 64) * IN_DIM + sc * 8;
    const unsigned short* Ha = Th + (size_t)(n0 + sr)      * KPAD   + sc * 8;
    const unsigned short* Hb = Th + (size_t)(n0 + sr + 64) * KPAD   + sc * 8;
    const unsigned short* La = Tl + (size_t)(n0 + sr)      * KPAD   + sc * 8;
    const unsigned short* Lb = Tl + (size_t)(n0 + sr + 64) * KPAD   + sc * 8;

    const float4 f4z = make_float4(0.f, 0.f, 0.f, 0.f);
    float4 xa0, xa1, xb0, xb1;
    uint4  vh0, vh1, vl0, vl1;

    f32x4 acc[4][4];
    #pragma unroll
    for (int i = 0; i < 4; ++i)
        #pragma unroll
        for (int j = 0; j < 4; ++j)
            acc[i][j] = (f32x4){0.f, 0.f, 0.f, 0.f};

    LOADTILE(0);
    STORETILE();
    __syncthreads();

    for (int it = 0; it < NITER; ++it) {
        bf16x8 af[4], bh[4], bl[4];
        #pragma unroll
        for (int i = 0; i < 4; ++i) {
            const int m = wm + i * 16 + ml;
            af[i] = *(const bf16x8*)&As[m * 32 + ((quad ^ ((m >> 1) & 3)) * 8)];
        }
        #pragma unroll
        for (int j = 0; j < 4; ++j) {
            const int n   = wn + j * 16 + ml;
            const int idx = n * 32 + ((quad ^ ((n >> 1) & 3)) * 8);
            bh[j] = *(const bf16x8*)&Bhs[idx];
            bl[j] = *(const bf16x8*)&Bls[idx];
        }

        const bool have_next = (it + 1 < NITER);
        if (have_next) LOADTILE((it + 1) * 32);

        #pragma unroll
        for (int i = 0; i < 4; ++i)
            #pragma unroll
            for (int j = 0; j < 4; ++j) {
                acc[i][j] = __builtin_amdgcn_mfma_f32_16x16x32_bf16(af[i], bh[j], acc[i][j], 0, 0, 0);
                acc[i][j] = __builtin_amdgcn_mfma_f32_16x16x32_bf16(af[i], bl[j], acc[i][j], 0, 0, 0);
            }

        __syncthreads();
        if (have_next) {
            STORETILE();
            __syncthreads();
        }
    }

    #pragma unroll
    for (int i = 0; i < 4; ++i)
        #pragma unroll
        for (int j = 0; j < 4; ++j) {
            const int row = m0 + wm + i * 16 + quad * 4;
            const int col = n0 + wn + j * 16 + ml;
            #pragma unroll
            for (int r = 0; r < 4; ++r)
                C[(size_t)(row + r) * HID_DIM + col] = acc[i][j][r];
        }
}

// ---------------------------------------------------------------------------
// LIF1 fused with GEMM2 — SCALAR layout: one thread per (b,h) channel
// (262144 threads = 16 waves/CU, 4x the float4 version's occupancy; that
// kernel was the hidden ~120 us tail: 210 MB at 1 block/CU). Depth-8
// rolling prefetch keeps ~6-8 loads in flight -> HBM-BW-bound (~40 us).
// Spike (threshold ~4.7 sigma, ~never) scatters W2 row into pre-zeroed
// outu via device-scope atomics — exact for any density.
// ---------------------------------------------------------------------------
__global__ __launch_bounds__(256) void lif1_fused(float* __restrict__ hid,
                                                  const float* __restrict__ W2,
                                                  float* __restrict__ outu) {
    const int idx = blockIdx.x * blockDim.x + threadIdx.x;   // 0..262143
    const int stride = BATCH * HID_DIM;                      // 262144
    const int b  = idx >> 10;
    const int h  = idx & 1023;

    float mem = 0.f;
    float u[8];
    #pragma unroll
    for (int c = 0; c < 8; ++c) u[c] = hid[c * stride + idx];

    for (int t = 0; t < T_STEPS; t += 4) {
        // process u[0..3]
        #pragma unroll
        for (int c = 0; c < 4; ++c) {
            mem = mem * DECAY + u[c];
            float s = (mem >= THRESH) ? 1.f : 0.f;
            mem -= s * THRESH;
            hid[(t + c) * stride + idx] = s;
            if (s != 0.f) {                                  // ~never taken
                float* od = outu + (size_t)(t + c) * (BATCH * OUT_DIM) + b * OUT_DIM;
                const float* w = W2 + (size_t)h * OUT_DIM;
                #pragma unroll
                for (int o = 0; o < OUT_DIM; ++o) atomicAdd(&od[o], w[o]);
            }
        }
        // shift window, issue next 4 loads (8 ahead of consumption)
        #pragma unroll
        for (int c = 0; c < 4; ++c) u[c] = u[c + 4];
        if (t + 8 < T_STEPS) {
            #pragma unroll
            for (int c = 0; c < 4; ++c) u[c + 4] = hid[(t + 8 + c) * stride + idx];
        }
    }
}

// ---------------------------------------------------------------------------
// LIF2: scan output membranes in place; depth-12 prefetch hides the serial
// scan latency (only 2560 threads -> latency, not BW, is the limit).
// ---------------------------------------------------------------------------
__global__ __launch_bounds__(256) void lif2(float* __restrict__ outp) {
    const int n = blockIdx.x * blockDim.x + threadIdx.x;
    const int stride = BATCH * OUT_DIM;                      // 2560
    if (n >= stride) return;
    float mem = 0.f;
    float u[12];
    #pragma unroll
    for (int c = 0; c < 12; ++c) u[c] = outp[c * stride + n];
    for (int t = 0; t < T_STEPS; t += 4) {
        #pragma unroll
        for (int c = 0; c < 4; ++c) {
            mem = mem * DECAY + u[c];
            float s = (mem >= THRESH) ? 1.f : 0.f;
            mem -= s * THRESH;
            outp[(t + c) * stride + n] = s;
        }
        #pragma unroll
        for (int c = 0; c < 8; ++c) u[c] = u[c + 4];
        if (t + 12 < T_STEPS) {
            #pragma unroll
            for (int c = 0; c < 4; ++c) u[c + 8] = outp[(t + 12 + c) * stride + n];
        }
    }
}

extern "C" void kernel_launch(void* const* d_in, const int* in_sizes, int n_in,
                              void* d_out, int out_size, void* d_ws, size_t ws_size,
                              hipStream_t stream) {
    const float* x  = (const float*)d_in[0];   // [T, B, I]
    const float* W1 = (const float*)d_in[1];   // [I, H]
    const float* W2 = (const float*)d_in[2];   // [H, O]
    float* out  = (float*)d_out;
    float* hid  = out;                                    // [T*B, H]
    float* outu = out + (size_t)M_ROWS * HID_DIM;         // [T*B, O]

    unsigned short* Th = (unsigned short*)d_ws;           // [1024][800] bf16
    unsigned short* Tl = Th + (size_t)HID_DIM * KPAD;     // [1024][800] bf16

    dim3 gt(HID_DIM / 32, KPAD / 32);
    w1_split_T<<<gt, 256, 0, stream>>>(W1, Th, Tl);

    hipMemsetAsync(outu, 0, (size_t)M_ROWS * OUT_DIM * sizeof(float), stream);

    gemm1_mfma<<<1600, 256, 0, stream>>>(x, Th, Tl, hid);

    lif1_fused<<<(BATCH * HID_DIM) / 256, 256, 0, stream>>>(hid, W2, outu);

    lif2<<<(BATCH * OUT_DIM + 255) / 256, 256, 0, stream>>>(outu);
}